// Round 8
// baseline (583.505 us; speedup 1.0000x reference)
//
#include <hip/hip_runtime.h>

#define N_NODES 50000
#define E_EDGES 800000
#define D_FEAT  96
#define C_CLS   40
#define N_ITER  8

#define SCAN_CHUNK 1024
#define SCAN_NB ((N_NODES + SCAN_CHUNK - 1) / SCAN_CHUNK)   // 49
#define DBINS 64

typedef short bf16x8 __attribute__((ext_vector_type(8)));   // 8 bf16 = 4 VGPRs
typedef float f32x4  __attribute__((ext_vector_type(4)));
typedef float f32x2  __attribute__((ext_vector_type(2)));

#if defined(__has_builtin)
#if __has_builtin(__builtin_amdgcn_cvt_pk_f32_fp8) && __has_builtin(__builtin_amdgcn_cvt_pk_fp8_f32)
#define HAVE_FP8_CVT 1
#endif
#endif
#ifndef HAVE_FP8_CVT
#define HAVE_FP8_CVT 0
#endif

// bf16 helpers (RNE)
static __device__ __forceinline__ unsigned short f2bf(float f) {
    unsigned u = __float_as_uint(f);
    u = (u + 0x7FFF + ((u >> 16) & 1)) >> 16;
    return (unsigned short)u;
}

// ---- fp8 e4m3fn manual fallback ----
static __device__ __forceinline__ unsigned f32_to_fp8_manual(float f) {
    unsigned u = __float_as_uint(f);
    unsigned s = u >> 31;
    int e8 = (int)((u >> 23) & 0xFF) - 127 + 7;
    unsigned m23 = u & 0x7FFFFF;
    if (e8 <= 0) return s << 7;
    if (e8 >= 15) return (s << 7) | 0x7E;
    unsigned m = m23 >> 20;
    unsigned rem = m23 & 0xFFFFF;
    if (rem > 0x80000u || (rem == 0x80000u && (m & 1))) {
        m++;
        if (m == 8) { m = 0; e8++; if (e8 >= 15) return (s << 7) | 0x7E; }
    }
    return (s << 7) | ((unsigned)e8 << 3) | m;
}
static __device__ __forceinline__ float fp8_to_f32_manual(unsigned b) {
    unsigned s = (b >> 7) & 1, e = (b >> 3) & 0xF, m = b & 7;
    if (e == 0) return 0.0f;
    return __uint_as_float((s << 31) | ((e + 120) << 23) | (m << 20));
}
static __device__ __forceinline__ void fp8x4_dec(unsigned w, float* o) {
#if HAVE_FP8_CVT
    f32x2 lo = __builtin_amdgcn_cvt_pk_f32_fp8(w, false);
    f32x2 hi = __builtin_amdgcn_cvt_pk_f32_fp8(w, true);
    o[0] = lo[0]; o[1] = lo[1]; o[2] = hi[0]; o[3] = hi[1];
#else
    o[0] = fp8_to_f32_manual(w & 0xFF);
    o[1] = fp8_to_f32_manual((w >> 8) & 0xFF);
    o[2] = fp8_to_f32_manual((w >> 16) & 0xFF);
    o[3] = fp8_to_f32_manual((w >> 24) & 0xFF);
#endif
}
static __device__ __forceinline__ unsigned fp8x4_enc(float a, float b, float c, float d) {
#if HAVE_FP8_CVT
    unsigned w = __builtin_amdgcn_cvt_pk_fp8_f32(a, b, 0, false);
    w = __builtin_amdgcn_cvt_pk_fp8_f32(c, d, (int)w, true);
    return w;
#else
    return f32_to_fp8_manual(a) | (f32_to_fp8_manual(b) << 8) |
           (f32_to_fp8_manual(c) << 16) | (f32_to_fp8_manual(d) << 24);
#endif
}

// ---------------------------------------------------------------------------
// CSR build, step 1: degree histogram
// ---------------------------------------------------------------------------
__global__ __launch_bounds__(256) void k_hist(const int* __restrict__ erow,
                                              int* __restrict__ deg) {
    int e = blockIdx.x * 256 + threadIdx.x;
    if (e >= E_EDGES) return;
    atomicAdd(&deg[erow[e]], 1);
}

// ---------------------------------------------------------------------------
// CSR scan 1/3: per-chunk reduction
// ---------------------------------------------------------------------------
__global__ __launch_bounds__(256) void k_scan_reduce(const int* __restrict__ deg,
                                                     int* __restrict__ bsum) {
    __shared__ int sbuf[256];
    int tid = threadIdx.x;
    int base = blockIdx.x * SCAN_CHUNK + tid * 4;
    int s = 0;
    #pragma unroll
    for (int j = 0; j < 4; ++j) {
        int idx = base + j;
        if (idx < N_NODES) s += deg[idx];
    }
    sbuf[tid] = s;
    __syncthreads();
    for (int d = 128; d > 0; d >>= 1) {
        if (tid < d) sbuf[tid] += sbuf[tid + d];
        __syncthreads();
    }
    if (tid == 0) bsum[blockIdx.x] = sbuf[0];
}

// ---------------------------------------------------------------------------
// CSR scan 2/3: exclusive scan of 49 block sums, one wave
// ---------------------------------------------------------------------------
__global__ __launch_bounds__(64) void k_scan_tops(int* __restrict__ bsum) {
    int lane = threadIdx.x;
    int v = (lane < SCAN_NB) ? bsum[lane] : 0;
    int inc = v;
    #pragma unroll
    for (int d = 1; d < 64; d <<= 1) {
        int up = __shfl_up(inc, d, 64);
        if (lane >= d) inc += up;
    }
    if (lane < SCAN_NB) bsum[lane] = inc - v;
}

// ---------------------------------------------------------------------------
// CSR scan 3/3: block-local scan + offset; ALSO accumulates the 64-bin
// degree histogram (for the degree-balanced node permutation).
// ---------------------------------------------------------------------------
__global__ __launch_bounds__(256) void k_scan_add(const int* __restrict__ deg,
                                                  const int* __restrict__ bsum_ex,
                                                  int* __restrict__ off,
                                                  int* __restrict__ cursor,
                                                  int* __restrict__ dh) {
    __shared__ int sbuf[256];
    __shared__ int lh[DBINS];
    int tid = threadIdx.x;
    if (tid < DBINS) lh[tid] = 0;
    int base = blockIdx.x * SCAN_CHUNK + tid * 4;
    int v[4];
    int s = 0;
    #pragma unroll
    for (int j = 0; j < 4; ++j) {
        int idx = base + j;
        v[j] = (idx < N_NODES) ? deg[idx] : 0;
        s += v[j];
    }
    sbuf[tid] = s;
    __syncthreads();
    for (int d = 1; d < 256; d <<= 1) {
        int t = (tid >= d) ? sbuf[tid - d] : 0;
        __syncthreads();
        sbuf[tid] += t;
        __syncthreads();
    }
    int ex = bsum_ex[blockIdx.x] + sbuf[tid] - s;
    #pragma unroll
    for (int j = 0; j < 4; ++j) {
        int idx = base + j;
        if (idx < N_NODES) {
            off[idx] = ex;
            cursor[idx] = ex;
            ex += v[j];
            atomicAdd(&lh[min(v[j], DBINS - 1)], 1);
        }
    }
    if (blockIdx.x == 0 && tid == 0) off[N_NODES] = E_EDGES;
    __syncthreads();
    if (tid < DBINS && lh[tid] != 0) atomicAdd(&dh[tid], lh[tid]);
}

// ---------------------------------------------------------------------------
// Degree-bin exclusive scan (one wave, 64 bins, in place)
// ---------------------------------------------------------------------------
__global__ __launch_bounds__(64) void k_dscan(int* __restrict__ dh) {
    int lane = threadIdx.x;
    int v = dh[lane];
    int inc = v;
    #pragma unroll
    for (int d = 1; d < 64; d <<= 1) {
        int up = __shfl_up(inc, d, 64);
        if (lane >= d) inc += up;
    }
    dh[lane] = inc - v;   // exclusive; reused as cursor by k_dscatter
}

// ---------------------------------------------------------------------------
// Scatter node ids into degree-sorted order -> perm
// ---------------------------------------------------------------------------
__global__ __launch_bounds__(256) void k_dscatter(const int* __restrict__ deg,
                                                  int* __restrict__ dh,
                                                  int* __restrict__ perm) {
    int n = blockIdx.x * 256 + threadIdx.x;
    if (n >= N_NODES) return;
    int d = min(deg[n], DBINS - 1);
    int pos = atomicAdd(&dh[d], 1);
    perm[pos] = n;
}

// ---------------------------------------------------------------------------
// CSR build, step 3: bucket-scatter packed edges (4B: col | bf16(val)<<16)
// ---------------------------------------------------------------------------
__global__ __launch_bounds__(256) void k_build(const int* __restrict__ erow,
                                               const int* __restrict__ ecol,
                                               const float* __restrict__ eval_,
                                               int* __restrict__ cursor,
                                               unsigned* __restrict__ epk) {
    int e = blockIdx.x * 256 + threadIdx.x;
    if (e >= E_EDGES) return;
    int r = erow[e];
    int pos = atomicAdd(&cursor[r], 1);
    unsigned pk = (unsigned)(ecol[e] & 0xFFFF) | ((unsigned)f2bf(eval_[e]) << 16);
    epk[pos] = pk;
}

// ---------------------------------------------------------------------------
// One-time: repack W_gc into MFMA B-fragment order, bf16.
// ---------------------------------------------------------------------------
__global__ __launch_bounds__(256) void k_prep_w(const float* __restrict__ W,
                                                unsigned short* __restrict__ WB) {
    for (int idx = threadIdx.x; idx < 18 * 64; idx += 256) {
        int grp = idx >> 6;
        int lane = idx & 63;
        int t = grp / 3, s = grp - t * 3;
        int n = t * 16 + (lane & 15);
        int k0 = s * 32 + (lane >> 4) * 8;
        unsigned short* dst = WB + (size_t)idx * 8;
        #pragma unroll
        for (int j = 0; j < 8; ++j)
            dst[j] = f2bf(W[(k0 + j) * D_FEAT + n]);
    }
}

// ---------------------------------------------------------------------------
// One-time: f32 -> bf16 row conversion (x at iteration 0)
// ---------------------------------------------------------------------------
__global__ __launch_bounds__(256) void k_cvt_bf16(const float* __restrict__ src,
                                                  unsigned short* __restrict__ dst,
                                                  int n8) {
    int g = blockIdx.x * 256 + threadIdx.x;
    if (g >= n8) return;
    const float4* s4 = (const float4*)src + (size_t)g * 2;
    float4 x0 = s4[0], x1 = s4[1];
    float vals[8] = {x0.x, x0.y, x0.z, x0.w, x1.x, x1.y, x1.z, x1.w};
    uint4 pk; unsigned* pku = (unsigned*)&pk;
    #pragma unroll
    for (int w2 = 0; w2 < 4; ++w2) {
        unsigned lo = f2bf(vals[w2 * 2 + 0]);
        unsigned hi = f2bf(vals[w2 * 2 + 1]);
        pku[w2] = lo | (hi << 16);
    }
    *(uint4*)(dst + (size_t)g * 8) = pk;
}

// ---------------------------------------------------------------------------
// Kernel 1: support(fp8) = hb(bf16) @ WB(bf16) via MFMA 16x16x32.
// ---------------------------------------------------------------------------
__global__ __launch_bounds__(256) void k_matmul_mfma(
        const unsigned short* __restrict__ hb,
        const unsigned short* __restrict__ WB,
        unsigned char* __restrict__ support) {
    __shared__ float sm[64 * 100];
    int tid = threadIdx.x;
    int wave = tid >> 6, lane = tid & 63;
    int q = lane >> 4, c = lane & 15;
    int m0 = blockIdx.x * 64 + wave * 16;

    if (m0 < N_NODES) {
        const unsigned short* arow = hb + (size_t)(m0 + c) * D_FEAT + q * 8;
        bf16x8 a0 = *(const bf16x8*)(arow);
        bf16x8 a1 = *(const bf16x8*)(arow + 32);
        bf16x8 a2 = *(const bf16x8*)(arow + 64);
        #pragma unroll
        for (int t = 0; t < 6; ++t) {
            const unsigned short* bp = WB + ((size_t)(t * 3) * 64 + lane) * 8;
            bf16x8 b0 = *(const bf16x8*)(bp);
            bf16x8 b1 = *(const bf16x8*)(bp + 64 * 8);
            bf16x8 b2 = *(const bf16x8*)(bp + 128 * 8);
            f32x4 acc = {0.f, 0.f, 0.f, 0.f};
            acc = __builtin_amdgcn_mfma_f32_16x16x32_bf16(a0, b0, acc, 0, 0, 0);
            acc = __builtin_amdgcn_mfma_f32_16x16x32_bf16(a1, b1, acc, 0, 0, 0);
            acc = __builtin_amdgcn_mfma_f32_16x16x32_bf16(a2, b2, acc, 0, 0, 0);
            #pragma unroll
            for (int r = 0; r < 4; ++r)
                sm[(wave * 16 + q * 4 + r) * 100 + t * 16 + c] = acc[r];
        }
    }
    __syncthreads();

    #pragma unroll
    for (int oo = 0; oo < 3; ++oo) {
        int o = tid + oo * 256;
        int row = o / 12;
        int cb = (o - row * 12) * 8;
        int grow = blockIdx.x * 64 + row;
        if (grow < N_NODES) {
            const float* sp = sm + row * 100 + cb;
            uint2 pk;
            pk.x = fp8x4_enc(sp[0], sp[1], sp[2], sp[3]);
            pk.y = fp8x4_enc(sp[4], sp[5], sp[6], sp[7]);
            *(uint2*)(support + (size_t)grow * D_FEAT + cb) = pk;
        }
    }
}

// ---------------------------------------------------------------------------
// Kernel 2 (fused agg+combine): degree-balanced via perm; 6 threads/node,
// 16 fp8 cols (16B load) each. bf16 state, in place.
// ---------------------------------------------------------------------------
__global__ __launch_bounds__(192) void k_agg(const int* __restrict__ off,
                                             const int* __restrict__ perm,
                                             const unsigned* __restrict__ epk,
                                             const unsigned char* __restrict__ support,
                                             const unsigned short* hin,
                                             const float* __restrict__ b,
                                             unsigned short* hout) {
    int gid = blockIdx.x * 192 + threadIdx.x;
    int ni = gid / 6;
    int q = gid % 6;             // 16-col group
    if (ni >= N_NODES) return;
    int n = perm[ni];

    int s = off[n];
    int e = off[n + 1];

    float acc[16];
    #pragma unroll
    for (int j = 0; j < 16; ++j) acc[j] = 0.0f;

    int i = s;
    for (; i < e && (i & 3); ++i) {
        unsigned p = epk[i];
        float v = __uint_as_float(p & 0xFFFF0000u);
        uint4 r = *(const uint4*)(support + (size_t)(p & 0xFFFFu) * D_FEAT + q * 16);
        float f[16];
        fp8x4_dec(r.x, f); fp8x4_dec(r.y, f + 4);
        fp8x4_dec(r.z, f + 8); fp8x4_dec(r.w, f + 12);
        #pragma unroll
        for (int j = 0; j < 16; ++j) acc[j] = fmaf(f[j], v, acc[j]);
    }
    for (; i + 4 <= e; i += 4) {
        uint4 pq = *(const uint4*)(epk + i);
        const unsigned* pp = (const unsigned*)&pq;
        uint4 r0 = *(const uint4*)(support + (size_t)(pp[0] & 0xFFFFu) * D_FEAT + q * 16);
        uint4 r1 = *(const uint4*)(support + (size_t)(pp[1] & 0xFFFFu) * D_FEAT + q * 16);
        uint4 r2 = *(const uint4*)(support + (size_t)(pp[2] & 0xFFFFu) * D_FEAT + q * 16);
        uint4 r3 = *(const uint4*)(support + (size_t)(pp[3] & 0xFFFFu) * D_FEAT + q * 16);
        float v0 = __uint_as_float(pp[0] & 0xFFFF0000u);
        float v1 = __uint_as_float(pp[1] & 0xFFFF0000u);
        float v2 = __uint_as_float(pp[2] & 0xFFFF0000u);
        float v3 = __uint_as_float(pp[3] & 0xFFFF0000u);
        float f[16];
        fp8x4_dec(r0.x, f); fp8x4_dec(r0.y, f + 4);
        fp8x4_dec(r0.z, f + 8); fp8x4_dec(r0.w, f + 12);
        #pragma unroll
        for (int j = 0; j < 16; ++j) acc[j] = fmaf(f[j], v0, acc[j]);
        fp8x4_dec(r1.x, f); fp8x4_dec(r1.y, f + 4);
        fp8x4_dec(r1.z, f + 8); fp8x4_dec(r1.w, f + 12);
        #pragma unroll
        for (int j = 0; j < 16; ++j) acc[j] = fmaf(f[j], v1, acc[j]);
        fp8x4_dec(r2.x, f); fp8x4_dec(r2.y, f + 4);
        fp8x4_dec(r2.z, f + 8); fp8x4_dec(r2.w, f + 12);
        #pragma unroll
        for (int j = 0; j < 16; ++j) acc[j] = fmaf(f[j], v2, acc[j]);
        fp8x4_dec(r3.x, f); fp8x4_dec(r3.y, f + 4);
        fp8x4_dec(r3.z, f + 8); fp8x4_dec(r3.w, f + 12);
        #pragma unroll
        for (int j = 0; j < 16; ++j) acc[j] = fmaf(f[j], v3, acc[j]);
    }
    for (; i < e; ++i) {
        unsigned p = epk[i];
        float v = __uint_as_float(p & 0xFFFF0000u);
        uint4 r = *(const uint4*)(support + (size_t)(p & 0xFFFFu) * D_FEAT + q * 16);
        float f[16];
        fp8x4_dec(r.x, f); fp8x4_dec(r.y, f + 4);
        fp8x4_dec(r.z, f + 8); fp8x4_dec(r.w, f + 12);
        #pragma unroll
        for (int j = 0; j < 16; ++j) acc[j] = fmaf(f[j], v, acc[j]);
    }

    // skip + bias + relu, bf16 state in/out (16 cols)
    const unsigned short* hrow = hin + (size_t)n * D_FEAT + q * 16;
    uint4 hq0 = *(const uint4*)(hrow);
    uint4 hq1 = *(const uint4*)(hrow + 8);
    const unsigned* hu0 = (const unsigned*)&hq0;
    const unsigned* hu1 = (const unsigned*)&hq1;
    const float* brow = b + q * 16;
    float og[16];
    #pragma unroll
    for (int w2 = 0; w2 < 4; ++w2) {
        float h0 = __uint_as_float(hu0[w2] << 16);
        float h1 = __uint_as_float(hu0[w2] & 0xFFFF0000u);
        og[w2*2+0] = fmaxf(0.5f * h0 + 0.5f * (acc[w2*2+0] + brow[w2*2+0]), 0.0f);
        og[w2*2+1] = fmaxf(0.5f * h1 + 0.5f * (acc[w2*2+1] + brow[w2*2+1]), 0.0f);
        float h2 = __uint_as_float(hu1[w2] << 16);
        float h3 = __uint_as_float(hu1[w2] & 0xFFFF0000u);
        og[8+w2*2+0] = fmaxf(0.5f * h2 + 0.5f * (acc[8+w2*2+0] + brow[8+w2*2+0]), 0.0f);
        og[8+w2*2+1] = fmaxf(0.5f * h3 + 0.5f * (acc[8+w2*2+1] + brow[8+w2*2+1]), 0.0f);
    }
    uint4 pk0, pk1;
    unsigned* pu0 = (unsigned*)&pk0;
    unsigned* pu1 = (unsigned*)&pk1;
    #pragma unroll
    for (int w2 = 0; w2 < 4; ++w2) {
        pu0[w2] = (unsigned)f2bf(og[w2*2+0]) | ((unsigned)f2bf(og[w2*2+1]) << 16);
        pu1[w2] = (unsigned)f2bf(og[8+w2*2+0]) | ((unsigned)f2bf(og[8+w2*2+1]) << 16);
    }
    unsigned short* orow = hout + (size_t)n * D_FEAT + q * 16;
    *(uint4*)(orow) = pk0;
    *(uint4*)(orow + 8) = pk1;
}

// ---------------------------------------------------------------------------
// Kernel 3: logits = bf16dec(hb) @ W_lin ; out = log_softmax (f32 math)
// ---------------------------------------------------------------------------
__global__ __launch_bounds__(256) void k_final(const unsigned short* __restrict__ hb,
                                               const float* __restrict__ Wg,
                                               float* __restrict__ out) {
    __shared__ float Wl[D_FEAT * C_CLS];
    {
        const float4* src = (const float4*)Wg;
        float4* dst = (float4*)Wl;
        for (int i = threadIdx.x; i < 960; i += 256) dst[i] = src[i];
    }
    __syncthreads();

    int n = blockIdx.x * 256 + threadIdx.x;
    if (n >= N_NODES) return;

    float acc[C_CLS];
    #pragma unroll
    for (int c = 0; c < C_CLS; ++c) acc[c] = 0.0f;

    const unsigned short* hrow = hb + (size_t)n * D_FEAT;
    for (int g = 0; g < 12; ++g) {
        uint4 hq = *(const uint4*)(hrow + g * 8);
        const unsigned* hu = (const unsigned*)&hq;
        float hv[8];
        #pragma unroll
        for (int w2 = 0; w2 < 4; ++w2) {
            hv[w2*2+0] = __uint_as_float(hu[w2] << 16);
            hv[w2*2+1] = __uint_as_float(hu[w2] & 0xFFFF0000u);
        }
        #pragma unroll
        for (int kk = 0; kk < 8; ++kk) {
            float hs = hv[kk];
            const float* wr = &Wl[(g * 8 + kk) * C_CLS];
            #pragma unroll
            for (int c4 = 0; c4 < 10; ++c4) {
                float4 w = *(const float4*)(wr + c4 * 4);
                acc[c4 * 4 + 0] = fmaf(hs, w.x, acc[c4 * 4 + 0]);
                acc[c4 * 4 + 1] = fmaf(hs, w.y, acc[c4 * 4 + 1]);
                acc[c4 * 4 + 2] = fmaf(hs, w.z, acc[c4 * 4 + 2]);
                acc[c4 * 4 + 3] = fmaf(hs, w.w, acc[c4 * 4 + 3]);
            }
        }
    }

    float m = acc[0];
    #pragma unroll
    for (int c = 1; c < C_CLS; ++c) m = fmaxf(m, acc[c]);
    float s = 0.0f;
    #pragma unroll
    for (int c = 0; c < C_CLS; ++c) s += expf(acc[c] - m);
    float lse = m + logf(s);

    float* orow = out + (size_t)n * C_CLS;
    #pragma unroll
    for (int c4 = 0; c4 < 10; ++c4)
        *(float4*)(orow + c4 * 4) =
            make_float4(acc[c4 * 4 + 0] - lse, acc[c4 * 4 + 1] - lse,
                        acc[c4 * 4 + 2] - lse, acc[c4 * 4 + 3] - lse);
}

// ---------------------------------------------------------------------------
static inline size_t align256(size_t x) { return (x + 255) & ~(size_t)255; }

extern "C" void kernel_launch(void* const* d_in, const int* in_sizes, int n_in,
                              void* d_out, int out_size, void* d_ws, size_t ws_size,
                              hipStream_t stream) {
    const float* x    = (const float*)d_in[0];
    const int*   erow = (const int*)  d_in[1];
    const int*   ecol = (const int*)  d_in[2];
    const float* ev   = (const float*)d_in[3];
    const float* Wgc  = (const float*)d_in[4];
    const float* bgc  = (const float*)d_in[5];
    const float* Wlin = (const float*)d_in[6];
    float* out = (float*)d_out;

    const size_t NF = (size_t)N_NODES * D_FEAT;
    char* ws = (char*)d_ws;
    unsigned short* hb         = (unsigned short*)ws; ws += align256(NF * 2);              // 9.6 MB
    unsigned short* xb         = (unsigned short*)ws; ws += align256(NF * 2);              // 9.6 MB
    unsigned char*  support_f8 = (unsigned char*)ws;  ws += align256(NF);                  // 4.8 MB
    unsigned*       epk        = (unsigned*)ws;       ws += align256((size_t)E_EDGES * 4); // 3.2 MB
    unsigned short* WB         = (unsigned short*)ws; ws += align256((size_t)18 * 64 * 8 * 2);
    int*            off        = (int*)ws;            ws += align256((size_t)(N_NODES + 1) * 4);
    int*            perm       = (int*)ws;            ws += align256((size_t)N_NODES * 4);
    int*            cursor     = (int*)ws;            ws += align256((size_t)N_NODES * 4);
    int*            bsum       = (int*)ws;            ws += align256((size_t)SCAN_NB * 4);
    // deg and dh adjacent: one memset covers both
    int*            deg        = (int*)ws;            ws += align256((size_t)N_NODES * 4);
    int*            dh         = (int*)ws;            ws += align256((size_t)DBINS * 4);

    // ---- one-time prep + CSR build + degree-balance perm ----
    hipMemsetAsync(deg, 0, align256((size_t)N_NODES * 4) + (size_t)DBINS * 4, stream);
    k_prep_w     <<<1, 256, 0, stream>>>(Wgc, WB);
    k_cvt_bf16   <<<(int)((NF / 8 + 255) / 256), 256, 0, stream>>>(x, xb, (int)(NF / 8));
    k_hist       <<<(E_EDGES + 255) / 256, 256, 0, stream>>>(erow, deg);
    k_scan_reduce<<<SCAN_NB, 256, 0, stream>>>(deg, bsum);
    k_scan_tops  <<<1, 64, 0, stream>>>(bsum);
    k_scan_add   <<<SCAN_NB, 256, 0, stream>>>(deg, bsum, off, cursor, dh);
    k_dscan      <<<1, 64, 0, stream>>>(dh);
    k_dscatter   <<<(N_NODES + 255) / 256, 256, 0, stream>>>(deg, dh, perm);
    k_build      <<<(E_EDGES + 255) / 256, 256, 0, stream>>>(erow, ecol, ev, cursor, epk);

    // ---- 8 GCN iterations (bf16 state hb, in-place) ----
    const int g_mm = (N_NODES + 63) / 64;
    const int g_ag = (N_NODES * 6 + 191) / 192;
    for (int it = 0; it < N_ITER; ++it) {
        const unsigned short* hin = (it == 0) ? xb : hb;
        k_matmul_mfma<<<g_mm, 256, 0, stream>>>(hin, WB, support_f8);
        k_agg        <<<g_ag, 192, 0, stream>>>(off, perm, epk, support_f8, hin, bgc, hb);
    }
    k_final<<<(N_NODES + 255) / 256, 256, 0, stream>>>(hb, Wlin, out);
}

// Round 9
// 373.679 us; speedup vs baseline: 1.5615x; 1.5615x over previous
//
#include <hip/hip_runtime.h>

#define N_NODES 50000
#define E_EDGES 800000
#define D_FEAT  96
#define C_CLS   40
#define N_ITER  8

#define NCHUNK 49          // ceil(50000/1024) node chunks
#define NB     256         // edge-partition blocks
#define EPB    3125        // edges per block (256*3125 = 800000 exactly)

typedef short bf16x8 __attribute__((ext_vector_type(8)));
typedef float f32x4  __attribute__((ext_vector_type(4)));
typedef float f32x2  __attribute__((ext_vector_type(2)));

#if defined(__has_builtin)
#if __has_builtin(__builtin_amdgcn_cvt_pk_f32_fp8) && __has_builtin(__builtin_amdgcn_cvt_pk_fp8_f32)
#define HAVE_FP8_CVT 1
#endif
#endif
#ifndef HAVE_FP8_CVT
#define HAVE_FP8_CVT 0
#endif

// bf16 helpers (RNE)
static __device__ __forceinline__ unsigned short f2bf(float f) {
    unsigned u = __float_as_uint(f);
    u = (u + 0x7FFF + ((u >> 16) & 1)) >> 16;
    return (unsigned short)u;
}

// ---- fp8 e4m3fn manual fallback ----
static __device__ __forceinline__ unsigned f32_to_fp8_manual(float f) {
    unsigned u = __float_as_uint(f);
    unsigned s = u >> 31;
    int e8 = (int)((u >> 23) & 0xFF) - 127 + 7;
    unsigned m23 = u & 0x7FFFFF;
    if (e8 <= 0) return s << 7;
    if (e8 >= 15) return (s << 7) | 0x7E;
    unsigned m = m23 >> 20;
    unsigned rem = m23 & 0xFFFFF;
    if (rem > 0x80000u || (rem == 0x80000u && (m & 1))) {
        m++;
        if (m == 8) { m = 0; e8++; if (e8 >= 15) return (s << 7) | 0x7E; }
    }
    return (s << 7) | ((unsigned)e8 << 3) | m;
}
static __device__ __forceinline__ float fp8_to_f32_manual(unsigned b) {
    unsigned s = (b >> 7) & 1, e = (b >> 3) & 0xF, m = b & 7;
    if (e == 0) return 0.0f;
    return __uint_as_float((s << 31) | ((e + 120) << 23) | (m << 20));
}
static __device__ __forceinline__ void fp8x4_dec(unsigned w, float* o) {
#if HAVE_FP8_CVT
    f32x2 lo = __builtin_amdgcn_cvt_pk_f32_fp8(w, false);
    f32x2 hi = __builtin_amdgcn_cvt_pk_f32_fp8(w, true);
    o[0] = lo[0]; o[1] = lo[1]; o[2] = hi[0]; o[3] = hi[1];
#else
    o[0] = fp8_to_f32_manual(w & 0xFF);
    o[1] = fp8_to_f32_manual((w >> 8) & 0xFF);
    o[2] = fp8_to_f32_manual((w >> 16) & 0xFF);
    o[3] = fp8_to_f32_manual((w >> 24) & 0xFF);
#endif
}
static __device__ __forceinline__ unsigned fp8x4_enc(float a, float b, float c, float d) {
#if HAVE_FP8_CVT
    unsigned w = __builtin_amdgcn_cvt_pk_fp8_f32(a, b, 0, false);
    w = __builtin_amdgcn_cvt_pk_fp8_f32(c, d, (int)w, true);
    return w;
#else
    return f32_to_fp8_manual(a) | (f32_to_fp8_manual(b) << 8) |
           (f32_to_fp8_manual(c) << 16) | (f32_to_fp8_manual(d) << 24);
#endif
}

// ---------------------------------------------------------------------------
// CSR phase A: per-block LDS histogram over 49 node-chunks -> cm[c*NB + b].
// No global atomics.
// ---------------------------------------------------------------------------
__global__ __launch_bounds__(256) void k_count(const int* __restrict__ erow,
                                               int* __restrict__ cm) {
    __shared__ int lcnt[NCHUNK];
    int b = blockIdx.x, tid = threadIdx.x;
    if (tid < NCHUNK) lcnt[tid] = 0;
    __syncthreads();
    int base = b * EPB;
    for (int i = tid; i < EPB; i += 256)
        atomicAdd(&lcnt[erow[base + i] >> 10], 1);
    __syncthreads();
    if (tid < NCHUNK) cm[tid * NB + b] = lcnt[tid];
}

// ---------------------------------------------------------------------------
// CSR phase B: in-place exclusive scan of cm (NCHUNK*NB = 12544 ints),
// chunk-major order. One block, 1024 threads, 13 elems/thread.
// ---------------------------------------------------------------------------
__global__ __launch_bounds__(1024) void k_cscan(int* __restrict__ cm) {
    __shared__ int sb[1024];
    const int TOT = NCHUNK * NB;
    const int PER = 13;                 // 13*1024 = 13312 >= 12544
    int tid = threadIdx.x;
    int base = tid * PER;
    int v[PER];
    int s = 0;
    #pragma unroll
    for (int j = 0; j < PER; ++j) {
        int idx = base + j;
        v[j] = (idx < TOT) ? cm[idx] : 0;
        s += v[j];
    }
    sb[tid] = s;
    __syncthreads();
    for (int d = 1; d < 1024; d <<= 1) {
        int t = (tid >= d) ? sb[tid - d] : 0;
        __syncthreads();
        sb[tid] += t;
        __syncthreads();
    }
    int ex = sb[tid] - s;
    #pragma unroll
    for (int j = 0; j < PER; ++j) {
        int idx = base + j;
        if (idx < TOT) { cm[idx] = ex; ex += v[j]; }
    }
}

// ---------------------------------------------------------------------------
// CSR phase C: re-read edges, write (colval, rowlocal) int2 into chunk-major
// staging at precomputed offsets. LDS cursors only; writes are ~512B runs.
// ---------------------------------------------------------------------------
__global__ __launch_bounds__(256) void k_scatter_runs(const int* __restrict__ erow,
                                                      const int* __restrict__ ecol,
                                                      const float* __restrict__ ev,
                                                      const int* __restrict__ cm,
                                                      int2* __restrict__ stag) {
    __shared__ int lcur[NCHUNK];
    int b = blockIdx.x, tid = threadIdx.x;
    if (tid < NCHUNK) lcur[tid] = cm[tid * NB + b];
    __syncthreads();
    int base = b * EPB;
    for (int i = tid; i < EPB; i += 256) {
        int e = base + i;
        int r = erow[e];
        int c = r >> 10;
        int pos = atomicAdd(&lcur[c], 1);
        int2 s;
        s.x = (int)((unsigned)(ecol[e] & 0xFFFF) | ((unsigned)f2bf(ev[e]) << 16));
        s.y = r & 1023;
        stag[pos] = s;
    }
}

// ---------------------------------------------------------------------------
// CSR phase D: per chunk (49 blocks x 1024 threads): LDS row-histogram ->
// LDS scan -> off[] + final row-grouped epk. Random writes confined to the
// chunk's ~64KB L2-resident window.
// ---------------------------------------------------------------------------
__global__ __launch_bounds__(1024) void k_chunk_csr(const int2* __restrict__ stag,
                                                    const int* __restrict__ cm,
                                                    unsigned* __restrict__ epk,
                                                    int* __restrict__ off) {
    __shared__ int lh[1024];
    __shared__ int lex[1024];
    __shared__ int sb[1024];
    int c = blockIdx.x, tid = threadIdx.x;
    int cb = cm[c * NB];
    int ce = (c + 1 < NCHUNK) ? cm[(c + 1) * NB] : E_EDGES;
    int m = ce - cb;

    lh[tid] = 0;
    __syncthreads();
    for (int i = tid; i < m; i += 1024) {
        int2 s = stag[cb + i];
        atomicAdd(&lh[s.y], 1);
    }
    __syncthreads();
    int v = lh[tid];
    sb[tid] = v;
    __syncthreads();
    for (int d = 1; d < 1024; d <<= 1) {
        int t = (tid >= d) ? sb[tid - d] : 0;
        __syncthreads();
        sb[tid] += t;
        __syncthreads();
    }
    int ex = sb[tid] - v;
    lex[tid] = ex;
    int node = c * 1024 + tid;
    if (node < N_NODES) off[node] = cb + ex;
    if (c == NCHUNK - 1 && tid == 0) off[N_NODES] = E_EDGES;
    __syncthreads();
    for (int i = tid; i < m; i += 1024) {
        int2 s = stag[cb + i];
        int pos = atomicAdd(&lex[s.y], 1);
        epk[cb + pos] = (unsigned)s.x;
    }
}

// ---------------------------------------------------------------------------
// One-time: repack W_gc into MFMA B-fragment order, bf16.
// ---------------------------------------------------------------------------
__global__ __launch_bounds__(256) void k_prep_w(const float* __restrict__ W,
                                                unsigned short* __restrict__ WB) {
    for (int idx = threadIdx.x; idx < 18 * 64; idx += 256) {
        int grp = idx >> 6;
        int lane = idx & 63;
        int t = grp / 3, s = grp - t * 3;
        int n = t * 16 + (lane & 15);
        int k0 = s * 32 + (lane >> 4) * 8;
        unsigned short* dst = WB + (size_t)idx * 8;
        #pragma unroll
        for (int j = 0; j < 8; ++j)
            dst[j] = f2bf(W[(k0 + j) * D_FEAT + n]);
    }
}

// ---------------------------------------------------------------------------
// One-time: f32 -> bf16 row conversion (x at iteration 0)
// ---------------------------------------------------------------------------
__global__ __launch_bounds__(256) void k_cvt_bf16(const float* __restrict__ src,
                                                  unsigned short* __restrict__ dst,
                                                  int n8) {
    int g = blockIdx.x * 256 + threadIdx.x;
    if (g >= n8) return;
    const float4* s4 = (const float4*)src + (size_t)g * 2;
    float4 x0 = s4[0], x1 = s4[1];
    float vals[8] = {x0.x, x0.y, x0.z, x0.w, x1.x, x1.y, x1.z, x1.w};
    uint4 pk; unsigned* pku = (unsigned*)&pk;
    #pragma unroll
    for (int w2 = 0; w2 < 4; ++w2) {
        unsigned lo = f2bf(vals[w2 * 2 + 0]);
        unsigned hi = f2bf(vals[w2 * 2 + 1]);
        pku[w2] = lo | (hi << 16);
    }
    *(uint4*)(dst + (size_t)g * 8) = pk;
}

// ---------------------------------------------------------------------------
// Kernel 1: support(fp8) = hb(bf16) @ WB(bf16) via MFMA 16x16x32.
// ---------------------------------------------------------------------------
__global__ __launch_bounds__(256) void k_matmul_mfma(
        const unsigned short* __restrict__ hb,
        const unsigned short* __restrict__ WB,
        unsigned char* __restrict__ support) {
    __shared__ float sm[64 * 100];
    int tid = threadIdx.x;
    int wave = tid >> 6, lane = tid & 63;
    int q = lane >> 4, c = lane & 15;
    int m0 = blockIdx.x * 64 + wave * 16;

    if (m0 < N_NODES) {
        const unsigned short* arow = hb + (size_t)(m0 + c) * D_FEAT + q * 8;
        bf16x8 a0 = *(const bf16x8*)(arow);
        bf16x8 a1 = *(const bf16x8*)(arow + 32);
        bf16x8 a2 = *(const bf16x8*)(arow + 64);
        #pragma unroll
        for (int t = 0; t < 6; ++t) {
            const unsigned short* bp = WB + ((size_t)(t * 3) * 64 + lane) * 8;
            bf16x8 b0 = *(const bf16x8*)(bp);
            bf16x8 b1 = *(const bf16x8*)(bp + 64 * 8);
            bf16x8 b2 = *(const bf16x8*)(bp + 128 * 8);
            f32x4 acc = {0.f, 0.f, 0.f, 0.f};
            acc = __builtin_amdgcn_mfma_f32_16x16x32_bf16(a0, b0, acc, 0, 0, 0);
            acc = __builtin_amdgcn_mfma_f32_16x16x32_bf16(a1, b1, acc, 0, 0, 0);
            acc = __builtin_amdgcn_mfma_f32_16x16x32_bf16(a2, b2, acc, 0, 0, 0);
            #pragma unroll
            for (int r = 0; r < 4; ++r)
                sm[(wave * 16 + q * 4 + r) * 100 + t * 16 + c] = acc[r];
        }
    }
    __syncthreads();

    #pragma unroll
    for (int oo = 0; oo < 3; ++oo) {
        int o = tid + oo * 256;
        int row = o / 12;
        int cb = (o - row * 12) * 8;
        int grow = blockIdx.x * 64 + row;
        if (grow < N_NODES) {
            const float* sp = sm + row * 100 + cb;
            uint2 pk;
            pk.x = fp8x4_enc(sp[0], sp[1], sp[2], sp[3]);
            pk.y = fp8x4_enc(sp[4], sp[5], sp[6], sp[7]);
            *(uint2*)(support + (size_t)grow * D_FEAT + cb) = pk;
        }
    }
}

// ---------------------------------------------------------------------------
// Kernel 2 (fused agg+combine): 6 threads/node, 16 fp8 cols (16B load) each.
// bf16 state, in place. Node order = natural (no perm).
// ---------------------------------------------------------------------------
__global__ __launch_bounds__(192) void k_agg(const int* __restrict__ off,
                                             const unsigned* __restrict__ epk,
                                             const unsigned char* __restrict__ support,
                                             const unsigned short* hin,
                                             const float* __restrict__ b,
                                             unsigned short* hout) {
    int gid = blockIdx.x * 192 + threadIdx.x;
    int n = gid / 6;
    int q = gid % 6;             // 16-col group
    if (n >= N_NODES) return;

    int s = off[n];
    int e = off[n + 1];

    float acc[16];
    #pragma unroll
    for (int j = 0; j < 16; ++j) acc[j] = 0.0f;

    int i = s;
    for (; i < e && (i & 3); ++i) {
        unsigned p = epk[i];
        float v = __uint_as_float(p & 0xFFFF0000u);
        uint4 r = *(const uint4*)(support + (size_t)(p & 0xFFFFu) * D_FEAT + q * 16);
        float f[16];
        fp8x4_dec(r.x, f); fp8x4_dec(r.y, f + 4);
        fp8x4_dec(r.z, f + 8); fp8x4_dec(r.w, f + 12);
        #pragma unroll
        for (int j = 0; j < 16; ++j) acc[j] = fmaf(f[j], v, acc[j]);
    }
    for (; i + 4 <= e; i += 4) {
        uint4 pq = *(const uint4*)(epk + i);
        const unsigned* pp = (const unsigned*)&pq;
        uint4 r0 = *(const uint4*)(support + (size_t)(pp[0] & 0xFFFFu) * D_FEAT + q * 16);
        uint4 r1 = *(const uint4*)(support + (size_t)(pp[1] & 0xFFFFu) * D_FEAT + q * 16);
        uint4 r2 = *(const uint4*)(support + (size_t)(pp[2] & 0xFFFFu) * D_FEAT + q * 16);
        uint4 r3 = *(const uint4*)(support + (size_t)(pp[3] & 0xFFFFu) * D_FEAT + q * 16);
        float v0 = __uint_as_float(pp[0] & 0xFFFF0000u);
        float v1 = __uint_as_float(pp[1] & 0xFFFF0000u);
        float v2 = __uint_as_float(pp[2] & 0xFFFF0000u);
        float v3 = __uint_as_float(pp[3] & 0xFFFF0000u);
        float f[16];
        fp8x4_dec(r0.x, f); fp8x4_dec(r0.y, f + 4);
        fp8x4_dec(r0.z, f + 8); fp8x4_dec(r0.w, f + 12);
        #pragma unroll
        for (int j = 0; j < 16; ++j) acc[j] = fmaf(f[j], v0, acc[j]);
        fp8x4_dec(r1.x, f); fp8x4_dec(r1.y, f + 4);
        fp8x4_dec(r1.z, f + 8); fp8x4_dec(r1.w, f + 12);
        #pragma unroll
        for (int j = 0; j < 16; ++j) acc[j] = fmaf(f[j], v1, acc[j]);
        fp8x4_dec(r2.x, f); fp8x4_dec(r2.y, f + 4);
        fp8x4_dec(r2.z, f + 8); fp8x4_dec(r2.w, f + 12);
        #pragma unroll
        for (int j = 0; j < 16; ++j) acc[j] = fmaf(f[j], v2, acc[j]);
        fp8x4_dec(r3.x, f); fp8x4_dec(r3.y, f + 4);
        fp8x4_dec(r3.z, f + 8); fp8x4_dec(r3.w, f + 12);
        #pragma unroll
        for (int j = 0; j < 16; ++j) acc[j] = fmaf(f[j], v3, acc[j]);
    }
    for (; i < e; ++i) {
        unsigned p = epk[i];
        float v = __uint_as_float(p & 0xFFFF0000u);
        uint4 r = *(const uint4*)(support + (size_t)(p & 0xFFFFu) * D_FEAT + q * 16);
        float f[16];
        fp8x4_dec(r.x, f); fp8x4_dec(r.y, f + 4);
        fp8x4_dec(r.z, f + 8); fp8x4_dec(r.w, f + 12);
        #pragma unroll
        for (int j = 0; j < 16; ++j) acc[j] = fmaf(f[j], v, acc[j]);
    }

    // skip + bias + relu, bf16 state in/out (16 cols)
    const unsigned short* hrow = hin + (size_t)n * D_FEAT + q * 16;
    uint4 hq0 = *(const uint4*)(hrow);
    uint4 hq1 = *(const uint4*)(hrow + 8);
    const unsigned* hu0 = (const unsigned*)&hq0;
    const unsigned* hu1 = (const unsigned*)&hq1;
    const float* brow = b + q * 16;
    float og[16];
    #pragma unroll
    for (int w2 = 0; w2 < 4; ++w2) {
        float h0 = __uint_as_float(hu0[w2] << 16);
        float h1 = __uint_as_float(hu0[w2] & 0xFFFF0000u);
        og[w2*2+0] = fmaxf(0.5f * h0 + 0.5f * (acc[w2*2+0] + brow[w2*2+0]), 0.0f);
        og[w2*2+1] = fmaxf(0.5f * h1 + 0.5f * (acc[w2*2+1] + brow[w2*2+1]), 0.0f);
        float h2 = __uint_as_float(hu1[w2] << 16);
        float h3 = __uint_as_float(hu1[w2] & 0xFFFF0000u);
        og[8+w2*2+0] = fmaxf(0.5f * h2 + 0.5f * (acc[8+w2*2+0] + brow[8+w2*2+0]), 0.0f);
        og[8+w2*2+1] = fmaxf(0.5f * h3 + 0.5f * (acc[8+w2*2+1] + brow[8+w2*2+1]), 0.0f);
    }
    uint4 pk0, pk1;
    unsigned* pu0 = (unsigned*)&pk0;
    unsigned* pu1 = (unsigned*)&pk1;
    #pragma unroll
    for (int w2 = 0; w2 < 4; ++w2) {
        pu0[w2] = (unsigned)f2bf(og[w2*2+0]) | ((unsigned)f2bf(og[w2*2+1]) << 16);
        pu1[w2] = (unsigned)f2bf(og[8+w2*2+0]) | ((unsigned)f2bf(og[8+w2*2+1]) << 16);
    }
    unsigned short* orow = hout + (size_t)n * D_FEAT + q * 16;
    *(uint4*)(orow) = pk0;
    *(uint4*)(orow + 8) = pk1;
}

// ---------------------------------------------------------------------------
// Kernel 3: logits = bf16dec(hb) @ W_lin ; out = log_softmax (f32 math)
// ---------------------------------------------------------------------------
__global__ __launch_bounds__(256) void k_final(const unsigned short* __restrict__ hb,
                                               const float* __restrict__ Wg,
                                               float* __restrict__ out) {
    __shared__ float Wl[D_FEAT * C_CLS];
    {
        const float4* src = (const float4*)Wg;
        float4* dst = (float4*)Wl;
        for (int i = threadIdx.x; i < 960; i += 256) dst[i] = src[i];
    }
    __syncthreads();

    int n = blockIdx.x * 256 + threadIdx.x;
    if (n >= N_NODES) return;

    float acc[C_CLS];
    #pragma unroll
    for (int c = 0; c < C_CLS; ++c) acc[c] = 0.0f;

    const unsigned short* hrow = hb + (size_t)n * D_FEAT;
    for (int g = 0; g < 12; ++g) {
        uint4 hq = *(const uint4*)(hrow + g * 8);
        const unsigned* hu = (const unsigned*)&hq;
        float hv[8];
        #pragma unroll
        for (int w2 = 0; w2 < 4; ++w2) {
            hv[w2*2+0] = __uint_as_float(hu[w2] << 16);
            hv[w2*2+1] = __uint_as_float(hu[w2] & 0xFFFF0000u);
        }
        #pragma unroll
        for (int kk = 0; kk < 8; ++kk) {
            float hs = hv[kk];
            const float* wr = &Wl[(g * 8 + kk) * C_CLS];
            #pragma unroll
            for (int c4 = 0; c4 < 10; ++c4) {
                float4 w = *(const float4*)(wr + c4 * 4);
                acc[c4 * 4 + 0] = fmaf(hs, w.x, acc[c4 * 4 + 0]);
                acc[c4 * 4 + 1] = fmaf(hs, w.y, acc[c4 * 4 + 1]);
                acc[c4 * 4 + 2] = fmaf(hs, w.z, acc[c4 * 4 + 2]);
                acc[c4 * 4 + 3] = fmaf(hs, w.w, acc[c4 * 4 + 3]);
            }
        }
    }

    float m = acc[0];
    #pragma unroll
    for (int c = 1; c < C_CLS; ++c) m = fmaxf(m, acc[c]);
    float s = 0.0f;
    #pragma unroll
    for (int c = 0; c < C_CLS; ++c) s += expf(acc[c] - m);
    float lse = m + logf(s);

    float* orow = out + (size_t)n * C_CLS;
    #pragma unroll
    for (int c4 = 0; c4 < 10; ++c4)
        *(float4*)(orow + c4 * 4) =
            make_float4(acc[c4 * 4 + 0] - lse, acc[c4 * 4 + 1] - lse,
                        acc[c4 * 4 + 2] - lse, acc[c4 * 4 + 3] - lse);
}

// ---------------------------------------------------------------------------
static inline size_t align256(size_t x) { return (x + 255) & ~(size_t)255; }

extern "C" void kernel_launch(void* const* d_in, const int* in_sizes, int n_in,
                              void* d_out, int out_size, void* d_ws, size_t ws_size,
                              hipStream_t stream) {
    const float* x    = (const float*)d_in[0];
    const int*   erow = (const int*)  d_in[1];
    const int*   ecol = (const int*)  d_in[2];
    const float* ev   = (const float*)d_in[3];
    const float* Wgc  = (const float*)d_in[4];
    const float* bgc  = (const float*)d_in[5];
    const float* Wlin = (const float*)d_in[6];
    float* out = (float*)d_out;

    const size_t NF = (size_t)N_NODES * D_FEAT;
    char* ws = (char*)d_ws;
    unsigned short* hb         = (unsigned short*)ws; ws += align256(NF * 2);              // 9.6 MB
    unsigned short* xb         = (unsigned short*)ws; ws += align256(NF * 2);              // 9.6 MB
    unsigned char*  support_f8 = (unsigned char*)ws;  ws += align256(NF);                  // 4.8 MB
    unsigned*       epk        = (unsigned*)ws;       ws += align256((size_t)E_EDGES * 4); // 3.2 MB
    int2*           stag       = (int2*)ws;           ws += align256((size_t)E_EDGES * 8); // 6.4 MB
    unsigned short* WB         = (unsigned short*)ws; ws += align256((size_t)18 * 64 * 8 * 2);
    int*            off        = (int*)ws;            ws += align256((size_t)(N_NODES + 1) * 4);
    int*            cm         = (int*)ws;            ws += align256((size_t)NCHUNK * NB * 4);

    // ---- one-time prep + atomic-free CSR build ----
    k_prep_w      <<<1, 256, 0, stream>>>(Wgc, WB);
    k_cvt_bf16    <<<(int)((NF / 8 + 255) / 256), 256, 0, stream>>>(x, xb, (int)(NF / 8));
    k_count       <<<NB, 256, 0, stream>>>(erow, cm);
    k_cscan       <<<1, 1024, 0, stream>>>(cm);
    k_scatter_runs<<<NB, 256, 0, stream>>>(erow, ecol, ev, cm, stag);
    k_chunk_csr   <<<NCHUNK, 1024, 0, stream>>>(stag, cm, epk, off);

    // ---- 8 GCN iterations (bf16 state hb, in-place) ----
    const int g_mm = (N_NODES + 63) / 64;
    const int g_ag = (N_NODES * 6 + 191) / 192;
    for (int it = 0; it < N_ITER; ++it) {
        const unsigned short* hin = (it == 0) ? xb : hb;
        k_matmul_mfma<<<g_mm, 256, 0, stream>>>(hin, WB, support_f8);
        k_agg        <<<g_ag, 192, 0, stream>>>(off, epk, support_f8, hin, bgc, hb);
    }
    k_final<<<(N_NODES + 255) / 256, 256, 0, stream>>>(hb, Wlin, out);
}